// Round 5
// baseline (240.010 us; speedup 1.0000x reference)
//
#include <hip/hip_runtime.h>
#include <hip/hip_bf16.h>

// IntraCellularAttention: B=1024, D_INNER=4096, D_STATE=16, D_ATTN=16
// out[b,d,s] = h[b,d,s] + gate * sum_t attn[b,s,t] * h[b,d,t]
// attn[s,t] = softmax_t( (Q K^T)[s,t] * 0.25 ),  Q[s,a] = sum_d h[b,d,s] Wq[a,d]
//
// Two-kernel split, 4 blocks per batch each, <=64 VGPR -> 32 waves/CU:
//   K1 (ica_qk): Q,K partial tiles per d-quarter via mfma_16x16x32_bf16,
//                2-slot pipeline, LDS wave-reduce, 512 floats -> ws.
//   K2 (ica_pv): reduce partials + softmax (redundant per quarter, trivial),
//                then out = h + PV via MFMA with hoisted B-frag (M, K=16
//                zero-padded to 32). Residual stays fp32.

constexpr int DI = 4096;
constexpr int DS = 16;

typedef __attribute__((ext_vector_type(8))) short bf16x8;
typedef __attribute__((ext_vector_type(4))) float f32x4;

static __device__ __forceinline__ short f2bf(float x) {
    union { __hip_bfloat16 h; short s; } u;
    u.h = __float2bfloat16(x);
    return u.s;
}

// ------------------------------------------------------------------ K1: Q,K
template<int SPLITS>
__global__ __launch_bounds__(256, 8) void ica_qk(
    const float* __restrict__ h,
    const float* __restrict__ Wq,
    const float* __restrict__ Wk,
    float* __restrict__ ws)
{
    constexpr int ROWS = DI / SPLITS;        // d-rows per block
    constexpr int NIT  = ROWS / 4 / 32;      // K=32 iters per wave
    const int blk  = blockIdx.x;
    const int b    = blk / SPLITS;
    const int sp   = blk % SPLITS;
    const int tid  = threadIdx.x;
    const int lane = tid & 63;
    const int wv   = tid >> 6;

    const float* __restrict__ hbase = h + (size_t)b * (DI * DS);
    const int d0w = sp * ROWS + wv * (ROWS / 4);

    __shared__ float qp[4][16][17];
    __shared__ float kp[4][16][17];

    const int sa = lane & 15;                // A row (s) / B row (a)
    const int kb = lane >> 4;                // k-subblock
    const float* __restrict__ wqb = Wq + (size_t)sa * DI;
    const float* __restrict__ wkb = Wk + (size_t)sa * DI;

    f32x4 accQ = {0.f, 0.f, 0.f, 0.f};
    f32x4 accK = {0.f, 0.f, 0.f, 0.f};

#define P1_LD(IT, A, Q0, Q1, K0, K1) do {                                   \
        const int db_ = d0w + (IT) * 32 + kb * 8;                           \
        const float* __restrict__ hp_ = hbase + (size_t)db_ * DS + sa;      \
        A[0] = hp_[0 * DS]; A[1] = hp_[1 * DS];                             \
        A[2] = hp_[2 * DS]; A[3] = hp_[3 * DS];                             \
        A[4] = hp_[4 * DS]; A[5] = hp_[5 * DS];                             \
        A[6] = hp_[6 * DS]; A[7] = hp_[7 * DS];                             \
        Q0 = *(const float4*)(wqb + db_); Q1 = *(const float4*)(wqb + db_ + 4); \
        K0 = *(const float4*)(wkb + db_); K1 = *(const float4*)(wkb + db_ + 4); \
    } while (0)

#define P1_FMA(A, Q0, Q1, K0, K1) do {                                      \
        bf16x8 af_, bq_, bk_;                                               \
        af_[0] = f2bf(A[0]); af_[1] = f2bf(A[1]);                           \
        af_[2] = f2bf(A[2]); af_[3] = f2bf(A[3]);                           \
        af_[4] = f2bf(A[4]); af_[5] = f2bf(A[5]);                           \
        af_[6] = f2bf(A[6]); af_[7] = f2bf(A[7]);                           \
        bq_[0] = f2bf(Q0.x); bq_[1] = f2bf(Q0.y);                           \
        bq_[2] = f2bf(Q0.z); bq_[3] = f2bf(Q0.w);                           \
        bq_[4] = f2bf(Q1.x); bq_[5] = f2bf(Q1.y);                           \
        bq_[6] = f2bf(Q1.z); bq_[7] = f2bf(Q1.w);                           \
        bk_[0] = f2bf(K0.x); bk_[1] = f2bf(K0.y);                           \
        bk_[2] = f2bf(K0.z); bk_[3] = f2bf(K0.w);                           \
        bk_[4] = f2bf(K1.x); bk_[5] = f2bf(K1.y);                           \
        bk_[6] = f2bf(K1.z); bk_[7] = f2bf(K1.w);                           \
        accQ = __builtin_amdgcn_mfma_f32_16x16x32_bf16(af_, bq_, accQ, 0, 0, 0); \
        accK = __builtin_amdgcn_mfma_f32_16x16x32_bf16(af_, bk_, accK, 0, 0, 0); \
    } while (0)

    {
        float A0[8], A1[8];
        float4 Q00, Q01, K00, K01;
        float4 Q10, Q11, K10, K11;
        P1_LD(0, A0, Q00, Q01, K00, K01);
        P1_LD(1, A1, Q10, Q11, K10, K11);
        for (int it = 0; it < NIT - 2; it += 2) {
            P1_FMA(A0, Q00, Q01, K00, K01);
            P1_LD(it + 2, A0, Q00, Q01, K00, K01);
            P1_FMA(A1, Q10, Q11, K10, K11);
            P1_LD(it + 3, A1, Q10, Q11, K10, K11);
        }
        P1_FMA(A0, Q00, Q01, K00, K01);
        P1_FMA(A1, Q10, Q11, K10, K11);
    }
#undef P1_LD
#undef P1_FMA

    // D mapping: col = lane&15 (=a), row = (lane>>4)*4+reg (=s)
    #pragma unroll
    for (int r = 0; r < 4; ++r) {
        qp[wv][kb * 4 + r][sa] = accQ[r];
        kp[wv][kb * 4 + r][sa] = accK[r];
    }
    __syncthreads();

    {
        const int s2 = tid >> 4, a2 = tid & 15;
        float q = qp[0][s2][a2] + qp[1][s2][a2] + qp[2][s2][a2] + qp[3][s2][a2];
        float k = kp[0][s2][a2] + kp[1][s2][a2] + kp[2][s2][a2] + kp[3][s2][a2];
        float* __restrict__ wsb = ws + (size_t)blk * 512;
        wsb[tid]       = q;     // Q[s*16+a]
        wsb[tid + 256] = k;     // K[s*16+a]
    }
}

// ------------------------------------------------------------------ K2: PV
template<int SPLITS>
__global__ __launch_bounds__(256, 8) void ica_pv(
    const float* __restrict__ h,
    const float* __restrict__ ws,
    const float* __restrict__ gate,
    float* __restrict__ out)
{
    constexpr int ROWS = DI / SPLITS;        // d-rows per block
    constexpr int NIT  = ROWS / 4 / 16;      // 16-row MFMA tiles per wave
    const int blk  = blockIdx.x;
    const int b    = blk / SPLITS;
    const int sp   = blk % SPLITS;
    const int tid  = threadIdx.x;
    const int lane = tid & 63;
    const int wv   = tid >> 6;

    const float* __restrict__ hbase = h   + (size_t)b * (DI * DS);
    float*       __restrict__ obase = out + (size_t)b * (DI * DS);

    __shared__ float Qs[16][20];
    __shared__ float Ks[16][20];
    __shared__ float Ms2[16][20];    // Ms2[s][t] = g * attn[s][t]

    // reduce the SPLITS partial tiles
    {
        const float* __restrict__ wsb = ws + (size_t)b * SPLITS * 512;
        float q = 0.f, k = 0.f;
        #pragma unroll
        for (int p = 0; p < SPLITS; ++p) {
            q += wsb[p * 512 + tid];
            k += wsb[p * 512 + 256 + tid];
        }
        Qs[tid >> 4][tid & 15] = q;
        Ks[tid >> 4][tid & 15] = k;
    }
    __syncthreads();

    // softmax + fold gate
    const float g = gate[0];
    {
        const int ss = tid >> 4;   // query slot
        const int tt = tid & 15;   // key slot
        float sc = 0.f;
        #pragma unroll
        for (int a4 = 0; a4 < 16; a4 += 4) {
            float4 qv = *(const float4*)&Qs[ss][a4];
            float4 kv = *(const float4*)&Ks[tt][a4];
            sc = fmaf(qv.x, kv.x, sc);
            sc = fmaf(qv.y, kv.y, sc);
            sc = fmaf(qv.z, kv.z, sc);
            sc = fmaf(qv.w, kv.w, sc);
        }
        sc *= 0.25f;  // D_ATTN^-0.5

        float m = sc;
        #pragma unroll
        for (int o = 8; o > 0; o >>= 1) m = fmaxf(m, __shfl_xor(m, o, 16));
        float e = __expf(sc - m);
        float sm = e;
        #pragma unroll
        for (int o = 8; o > 0; o >>= 1) sm += __shfl_xor(sm, o, 16);
        Ms2[ss][tt] = g * (e / sm);
    }
    __syncthreads();

    // hoisted B fragment: B[k=t][col=s] = Ms2[s][t], zero for t>=16
    const int c  = lane & 15;
    const int kb = lane >> 4;
    bf16x8 bfrag = {0, 0, 0, 0, 0, 0, 0, 0};
    if (kb < 2) {
        const float* mp = &Ms2[c][kb * 8];
        float4 m0 = *(const float4*)mp;
        float4 m1 = *(const float4*)(mp + 4);
        bfrag[0] = f2bf(m0.x); bfrag[1] = f2bf(m0.y);
        bfrag[2] = f2bf(m0.z); bfrag[3] = f2bf(m0.w);
        bfrag[4] = f2bf(m1.x); bfrag[5] = f2bf(m1.y);
        bfrag[6] = f2bf(m1.z); bfrag[7] = f2bf(m1.w);
    }

    const int rbase = sp * ROWS + wv * (ROWS / 4);

    // A prefetch (1 tile ahead); kb>=2 lanes carry zeros (K padding)
    float4 a0n = {0.f, 0.f, 0.f, 0.f}, a1n = {0.f, 0.f, 0.f, 0.f};
    if (kb < 2) {
        const float* hr = hbase + (size_t)(rbase + c) * DS + kb * 8;
        a0n = *(const float4*)hr;
        a1n = *(const float4*)(hr + 4);
    }

    for (int it = 0; it < NIT; ++it) {
        float4 a0 = a0n, a1 = a1n;
        if (it + 1 < NIT && kb < 2) {
            const float* hr = hbase + (size_t)(rbase + (it + 1) * 16 + c) * DS + kb * 8;
            a0n = *(const float4*)hr;
            a1n = *(const float4*)(hr + 4);
        }
        // residual loads (independent of MFMA)
        const int rr = rbase + it * 16 + kb * 4;
        float h0 = hbase[(size_t)(rr + 0) * DS + c];
        float h1 = hbase[(size_t)(rr + 1) * DS + c];
        float h2 = hbase[(size_t)(rr + 2) * DS + c];
        float h3 = hbase[(size_t)(rr + 3) * DS + c];

        bf16x8 af;
        af[0] = f2bf(a0.x); af[1] = f2bf(a0.y); af[2] = f2bf(a0.z); af[3] = f2bf(a0.w);
        af[4] = f2bf(a1.x); af[5] = f2bf(a1.y); af[6] = f2bf(a1.z); af[7] = f2bf(a1.w);

        f32x4 acc = {0.f, 0.f, 0.f, 0.f};
        acc = __builtin_amdgcn_mfma_f32_16x16x32_bf16(af, bfrag, acc, 0, 0, 0);

        __builtin_nontemporal_store(h0 + acc[0], &obase[(size_t)(rr + 0) * DS + c]);
        __builtin_nontemporal_store(h1 + acc[1], &obase[(size_t)(rr + 1) * DS + c]);
        __builtin_nontemporal_store(h2 + acc[2], &obase[(size_t)(rr + 2) * DS + c]);
        __builtin_nontemporal_store(h3 + acc[3], &obase[(size_t)(rr + 3) * DS + c]);
    }
}

// ----------------------------------------------- fused fallback (round-4)
__global__ __launch_bounds__(256, 4) void ica_fused(
    const float* __restrict__ h,
    const float* __restrict__ Wq,
    const float* __restrict__ Wk,
    const float* __restrict__ gate,
    float* __restrict__ out)
{
    const int b    = blockIdx.x;
    const int tid  = threadIdx.x;
    const int lane = tid & 63;
    const int wv   = tid >> 6;

    const float* __restrict__ hbase = h   + (size_t)b * (DI * DS);
    float*       __restrict__ obase = out + (size_t)b * (DI * DS);

    __shared__ float qp[4][16][20];
    __shared__ float kp[4][16][20];
    __shared__ float Qs[DS][20];
    __shared__ float Ks[DS][20];
    __shared__ float Ms[DS][20];

    {
        const int sa = lane & 15;
        const int kb = lane >> 4;
        f32x4 accQ = {0.f, 0.f, 0.f, 0.f};
        f32x4 accK = {0.f, 0.f, 0.f, 0.f};
        const int d0w = wv * (DI / 4);
        for (int it = 0; it < (DI / 4) / 32; ++it) {
            const int db = d0w + it * 32 + kb * 8;
            const float* __restrict__ hp = hbase + (size_t)db * DS + sa;
            float a0 = hp[0 * DS], a1 = hp[1 * DS], a2 = hp[2 * DS], a3 = hp[3 * DS];
            float a4 = hp[4 * DS], a5 = hp[5 * DS], a6 = hp[6 * DS], a7 = hp[7 * DS];
            const float* __restrict__ wqr = Wq + (size_t)sa * DI + db;
            const float* __restrict__ wkr = Wk + (size_t)sa * DI + db;
            float4 q0 = *(const float4*)(wqr);
            float4 q1 = *(const float4*)(wqr + 4);
            float4 k0 = *(const float4*)(wkr);
            float4 k1 = *(const float4*)(wkr + 4);
            bf16x8 af, bq, bk;
            af[0] = f2bf(a0);  af[1] = f2bf(a1);  af[2] = f2bf(a2);  af[3] = f2bf(a3);
            af[4] = f2bf(a4);  af[5] = f2bf(a5);  af[6] = f2bf(a6);  af[7] = f2bf(a7);
            bq[0] = f2bf(q0.x); bq[1] = f2bf(q0.y); bq[2] = f2bf(q0.z); bq[3] = f2bf(q0.w);
            bq[4] = f2bf(q1.x); bq[5] = f2bf(q1.y); bq[6] = f2bf(q1.z); bq[7] = f2bf(q1.w);
            bk[0] = f2bf(k0.x); bk[1] = f2bf(k0.y); bk[2] = f2bf(k0.z); bk[3] = f2bf(k0.w);
            bk[4] = f2bf(k1.x); bk[5] = f2bf(k1.y); bk[6] = f2bf(k1.z); bk[7] = f2bf(k1.w);
            accQ = __builtin_amdgcn_mfma_f32_16x16x32_bf16(af, bq, accQ, 0, 0, 0);
            accK = __builtin_amdgcn_mfma_f32_16x16x32_bf16(af, bk, accK, 0, 0, 0);
        }
        #pragma unroll
        for (int r = 0; r < 4; ++r) {
            qp[wv][(lane >> 4) * 4 + r][lane & 15] = accQ[r];
            kp[wv][(lane >> 4) * 4 + r][lane & 15] = accK[r];
        }
    }
    __syncthreads();
    {
        const int s = tid >> 4, a = tid & 15;
        Qs[s][a] = qp[0][s][a] + qp[1][s][a] + qp[2][s][a] + qp[3][s][a];
        Ks[s][a] = kp[0][s][a] + kp[1][s][a] + kp[2][s][a] + kp[3][s][a];
    }
    __syncthreads();
    const float g = gate[0];
    {
        const int ss = tid >> 4;
        const int tt = tid & 15;
        float sc = 0.f;
        #pragma unroll
        for (int a4 = 0; a4 < 16; a4 += 4) {
            float4 qv = *(const float4*)&Qs[ss][a4];
            float4 kv = *(const float4*)&Ks[tt][a4];
            sc = fmaf(qv.x, kv.x, sc);
            sc = fmaf(qv.y, kv.y, sc);
            sc = fmaf(qv.z, kv.z, sc);
            sc = fmaf(qv.w, kv.w, sc);
        }
        sc *= 0.25f;
        float m = sc;
        #pragma unroll
        for (int o = 8; o > 0; o >>= 1) m = fmaxf(m, __shfl_xor(m, o, 16));
        float e = __expf(sc - m);
        float sm = e;
        #pragma unroll
        for (int o = 8; o > 0; o >>= 1) sm += __shfl_xor(sm, o, 16);
        float attn = e / sm;
        Ms[tt][ss] = ((ss == tt) ? 1.f : 0.f) + g * attn;
    }
    __syncthreads();
    {
        const int sq = tid & 3;
        const int r0 = tid >> 2;
        f32x4 M4[16];
        #pragma unroll
        for (int tp = 0; tp < 16; ++tp)
            M4[tp] = *(const f32x4*)&Ms[tp][sq * 4];
        for (int r = r0; r < DI; r += 64) {
            const f32x4* __restrict__ hr = (const f32x4*)(hbase + (size_t)r * DS);
            f32x4 c0 = hr[0], c1 = hr[1], c2 = hr[2], c3 = hr[3];
            f32x4 acc = {0.f, 0.f, 0.f, 0.f};
            #define AC4(hsc, MM)                                            \
                acc[0] = fmaf(hsc, (MM)[0], acc[0]);                        \
                acc[1] = fmaf(hsc, (MM)[1], acc[1]);                        \
                acc[2] = fmaf(hsc, (MM)[2], acc[2]);                        \
                acc[3] = fmaf(hsc, (MM)[3], acc[3]);
            AC4(c0[0], M4[0])  AC4(c0[1], M4[1])
            AC4(c0[2], M4[2])  AC4(c0[3], M4[3])
            AC4(c1[0], M4[4])  AC4(c1[1], M4[5])
            AC4(c1[2], M4[6])  AC4(c1[3], M4[7])
            AC4(c2[0], M4[8])  AC4(c2[1], M4[9])
            AC4(c2[2], M4[10]) AC4(c2[3], M4[11])
            AC4(c3[0], M4[12]) AC4(c3[1], M4[13])
            AC4(c3[2], M4[14]) AC4(c3[3], M4[15])
            #undef AC4
            *(f32x4*)(obase + (size_t)r * DS + sq * 4) = acc;
        }
    }
}

extern "C" void kernel_launch(void* const* d_in, const int* in_sizes, int n_in,
                              void* d_out, int out_size, void* d_ws, size_t ws_size,
                              hipStream_t stream) {
    const float* h    = (const float*)d_in[0];
    const float* Wq   = (const float*)d_in[1];
    const float* Wk   = (const float*)d_in[2];
    const float* gate = (const float*)d_in[3];
    float* out = (float*)d_out;
    float* wsf = (float*)d_ws;
    (void)in_sizes; (void)n_in; (void)out_size;

    const size_t need4 = (size_t)1024 * 4 * 512 * sizeof(float);  // 8 MiB
    const size_t need2 = need4 / 2;
    const size_t need1 = need4 / 4;

    if (ws_size >= need4) {
        ica_qk<4><<<4096, 256, 0, stream>>>(h, Wq, Wk, wsf);
        ica_pv<4><<<4096, 256, 0, stream>>>(h, wsf, gate, out);
    } else if (ws_size >= need2) {
        ica_qk<2><<<2048, 256, 0, stream>>>(h, Wq, Wk, wsf);
        ica_pv<2><<<2048, 256, 0, stream>>>(h, wsf, gate, out);
    } else if (ws_size >= need1) {
        ica_qk<1><<<1024, 256, 0, stream>>>(h, Wq, Wk, wsf);
        ica_pv<1><<<1024, 256, 0, stream>>>(h, wsf, gate, out);
    } else {
        ica_fused<<<1024, 256, 0, stream>>>(h, Wq, Wk, gate, out);
    }
}